// Round 2
// baseline (203.493 us; speedup 1.0000x reference)
//
#include <hip/hip_runtime.h>

#define NROWS 32

// ---------------------------------------------------------------------------
// Kernel 1: per-row scan of batch_x -> cut positions + segment counts.
// One block per row, 256 threads. Coalesced: chunk c loads token c*256+tid.
// Ballot + popcount gives each cut its ordinal without a 256-wide LDS scan.
// ---------------------------------------------------------------------------
__global__ __launch_bounds__(256) void find_cuts_kernel(
    const int* __restrict__ batch_x, int T, int maxlen,
    int* __restrict__ cut_pos,      // [B, maxlen]
    int* __restrict__ n_cuts_i,     // [B]
    float* __restrict__ n_cuts_out) // [B], fp32 tail of d_out
{
    const int b = blockIdx.x;
    const int tid = threadIdx.x;
    const int lane = tid & 63;
    const int w = tid >> 6;                    // wave 0..3
    const int* row = batch_x + (long long)b * T;

    __shared__ int wave_cnt[4];
    int base = 0;                              // cuts seen in previous chunks

    for (int c = 0; c < T; c += 256) {
        const int t = c + tid;
        const int is_cut = (t < T) ? (row[t] == 1) : 0;
        const unsigned long long m = __ballot(is_cut);
        if (lane == 0) wave_cnt[w] = __popcll(m);
        __syncthreads();
        const int w0 = wave_cnt[0], w1 = wave_cnt[1],
                  w2 = wave_cnt[2], w3 = wave_cnt[3];
        const int wbase = (w > 0 ? w0 : 0) + (w > 1 ? w1 : 0) + (w > 2 ? w2 : 0);
        if (is_cut) {
            const int before = __popcll(m & ((1ull << lane) - 1ull));
            cut_pos[b * maxlen + base + wbase + before] = t;
        }
        base += w0 + w1 + w2 + w3;
        __syncthreads();                       // protect wave_cnt for next chunk
    }
    if (tid == 0) {
        n_cuts_i[b] = base;
        n_cuts_out[b] = (float)base;
    }
}

// ---------------------------------------------------------------------------
// Kernel 2: mean-pool each segment. One wave (64 lanes) per (row, segment);
// lane l owns features [4l, 4l+4) as a float4 (requires E == 256).
// Unrolled x4 with independent accumulators for memory-level parallelism.
// ---------------------------------------------------------------------------
__global__ __launch_bounds__(256) void pool_kernel(
    const float* __restrict__ nn,
    const int* __restrict__ cut_pos,
    const int* __restrict__ n_cuts_i,
    int T, int E, int maxlen,
    float* __restrict__ out)
{
    const int wave = (int)((blockIdx.x * (long long)blockDim.x + threadIdx.x) >> 6);
    const int lane = threadIdx.x & 63;
    const int total = NROWS * maxlen;
    if (wave >= total) return;
    const int b = wave / maxlen;
    const int k = wave - b * maxlen;

    const int nc = n_cuts_i[b];
    float4 acc = make_float4(0.f, 0.f, 0.f, 0.f);
    float inv = 0.f;
    if (k < nc) {
        const int start = (k == 0) ? 0 : (cut_pos[b * maxlen + k - 1] + 1);
        const int end   = cut_pos[b * maxlen + k];   // inclusive
        const int cnt   = end - start + 1;
        const float* base = nn + ((long long)b * T + start) * E + lane * 4;

        float4 a0 = make_float4(0.f, 0.f, 0.f, 0.f);
        float4 a1 = a0, a2 = a0, a3 = a0;
        int t = 0;
        for (; t + 4 <= cnt; t += 4) {
            const float4 v0 = *(const float4*)(base + (long long)(t + 0) * E);
            const float4 v1 = *(const float4*)(base + (long long)(t + 1) * E);
            const float4 v2 = *(const float4*)(base + (long long)(t + 2) * E);
            const float4 v3 = *(const float4*)(base + (long long)(t + 3) * E);
            a0.x += v0.x; a0.y += v0.y; a0.z += v0.z; a0.w += v0.w;
            a1.x += v1.x; a1.y += v1.y; a1.z += v1.z; a1.w += v1.w;
            a2.x += v2.x; a2.y += v2.y; a2.z += v2.z; a2.w += v2.w;
            a3.x += v3.x; a3.y += v3.y; a3.z += v3.z; a3.w += v3.w;
        }
        for (; t < cnt; ++t) {
            const float4 v = *(const float4*)(base + (long long)t * E);
            a0.x += v.x; a0.y += v.y; a0.z += v.z; a0.w += v.w;
        }
        acc.x = (a0.x + a1.x) + (a2.x + a3.x);
        acc.y = (a0.y + a1.y) + (a2.y + a3.y);
        acc.z = (a0.z + a1.z) + (a2.z + a3.z);
        acc.w = (a0.w + a1.w) + (a2.w + a3.w);
        inv = 1.0f / (float)cnt;
    }
    acc.x *= inv; acc.y *= inv; acc.z *= inv; acc.w *= inv;
    float4* o = (float4*)(out + ((long long)b * maxlen + k) * E) + lane;
    *o = acc;
}

extern "C" void kernel_launch(void* const* d_in, const int* in_sizes, int n_in,
                              void* d_out, int out_size, void* d_ws, size_t ws_size,
                              hipStream_t stream) {
    const float* nn_outs = (const float*)d_in[0];
    const int*   batch_x = (const int*)d_in[1];
    float* out = (float*)d_out;

    const int B = NROWS;
    const long long bt = in_sizes[1];            // B*T
    const int T = (int)(bt / B);                 // 4096
    const int E = (int)(in_sizes[0] / bt);       // 256
    const int maxlen = (out_size - B) / (B * E); // 256

    // workspace layout: cut_pos [B*maxlen] ints, n_cuts [B] ints
    int* cut_pos = (int*)d_ws;
    int* n_cuts_i = cut_pos + (size_t)B * maxlen;
    float* n_cuts_out = out + (size_t)B * maxlen * E;   // tail of d_out

    find_cuts_kernel<<<B, 256, 0, stream>>>(batch_x, T, maxlen,
                                            cut_pos, n_cuts_i, n_cuts_out);

    const int total_waves = B * maxlen;          // one wave per segment
    const int blocks = (total_waves + 3) / 4;    // 4 waves (256 thr) per block
    pool_kernel<<<blocks, 256, 0, stream>>>(nn_outs, cut_pos, n_cuts_i,
                                            T, E, maxlen, out);
}

// Round 3
// 191.767 us; speedup vs baseline: 1.0611x; 1.0611x over previous
//
#include <hip/hip_runtime.h>

// Problem shape (fixed by the reference): B=32, T=4096, E=256.
#define NROWS 32
#define TLEN  4096
#define EDIM  256
#define PER   (TLEN / 256)      // tokens per thread in the scan = 16
#define SEGS_PER_BLOCK 4        // one segment per wave, 4 waves/block

// ---------------------------------------------------------------------------
// Fused kernel: each block (256 threads) handles 4 segments of one row.
// Phase 1: the block redundantly scans the row's batch_x (16 KB, L2-hot
//          across the 64 blocks of the same row) into LDS cut positions.
//          int4 vector loads; shuffle-based wave prefix; single sync.
// Phase 2: wave w mean-pools segment k0+w. Lane l owns a float4 of features;
//          each wave streams 16 KB contiguous, fully coalesced.
// ---------------------------------------------------------------------------
__global__ __launch_bounds__(256) void fused_pool_kernel(
    const float* __restrict__ nn,
    const int*  __restrict__ batch_x,
    int maxlen, int nb_per_row,
    float* __restrict__ out,         // [B, maxlen, E]
    float* __restrict__ n_cuts_out)  // [B] fp32 tail of d_out
{
    const int tid  = threadIdx.x;
    const int lane = tid & 63;
    const int w    = tid >> 6;
    const int blk  = blockIdx.x;
    const int b    = blk / nb_per_row;
    const int k0   = (blk - b * nb_per_row) * SEGS_PER_BLOCK;

    // ---- Phase 1: scan row b ----
    __shared__ int s_cuts[TLEN];     // cut positions (worst case T cuts)
    __shared__ int s_wsum[4];

    const int* row = batch_x + (long long)b * TLEN;
    const int t0 = tid * PER;

    int flags[PER];
#pragma unroll
    for (int j = 0; j < PER; j += 4) {
        const int4 v = *(const int4*)(row + t0 + j);   // 64B-aligned
        flags[j] = v.x; flags[j + 1] = v.y; flags[j + 2] = v.z; flags[j + 3] = v.w;
    }
    int local = 0;
#pragma unroll
    for (int j = 0; j < PER; ++j) local += (flags[j] == 1);

    // wave-level inclusive prefix sum (6 shuffle steps, no sync)
    int incl = local;
#pragma unroll
    for (int d = 1; d < 64; d <<= 1) {
        const int v = __shfl_up(incl, d, 64);
        if (lane >= d) incl += v;
    }
    if (lane == 63) s_wsum[w] = incl;
    __syncthreads();
    const int s0 = s_wsum[0], s1 = s_wsum[1], s2 = s_wsum[2], s3 = s_wsum[3];
    const int wbase = (w > 0 ? s0 : 0) + (w > 1 ? s1 : 0) + (w > 2 ? s2 : 0);
    const int ncuts = s0 + s1 + s2 + s3;

    int idx = wbase + incl - local;  // exclusive prefix for this thread
#pragma unroll
    for (int j = 0; j < PER; ++j)
        if (flags[j] == 1) s_cuts[idx++] = t0 + j;
    __syncthreads();

    if (k0 == 0 && tid == 0) n_cuts_out[b] = (float)ncuts;

    // ---- Phase 2: pool segment k = k0 + w ----
    const int k = k0 + w;
    if (k >= maxlen) return;

    float4 acc = make_float4(0.f, 0.f, 0.f, 0.f);
    float inv = 0.f;
    if (k < ncuts) {
        const int start = (k == 0) ? 0 : (s_cuts[k - 1] + 1);
        const int end   = s_cuts[k];                  // inclusive
        const int cnt   = end - start + 1;
        const float* base = nn + ((long long)b * TLEN + start) * EDIM + lane * 4;

        float4 a0 = make_float4(0.f, 0.f, 0.f, 0.f);
        float4 a1 = a0, a2 = a0, a3 = a0;
        int t = 0;
        for (; t + 4 <= cnt; t += 4) {
            const float4 v0 = *(const float4*)(base + (long long)(t + 0) * EDIM);
            const float4 v1 = *(const float4*)(base + (long long)(t + 1) * EDIM);
            const float4 v2 = *(const float4*)(base + (long long)(t + 2) * EDIM);
            const float4 v3 = *(const float4*)(base + (long long)(t + 3) * EDIM);
            a0.x += v0.x; a0.y += v0.y; a0.z += v0.z; a0.w += v0.w;
            a1.x += v1.x; a1.y += v1.y; a1.z += v1.z; a1.w += v1.w;
            a2.x += v2.x; a2.y += v2.y; a2.z += v2.z; a2.w += v2.w;
            a3.x += v3.x; a3.y += v3.y; a3.z += v3.z; a3.w += v3.w;
        }
        for (; t < cnt; ++t) {
            const float4 v = *(const float4*)(base + (long long)t * EDIM);
            a0.x += v.x; a0.y += v.y; a0.z += v.z; a0.w += v.w;
        }
        acc.x = (a0.x + a1.x) + (a2.x + a3.x);
        acc.y = (a0.y + a1.y) + (a2.y + a3.y);
        acc.z = (a0.z + a1.z) + (a2.z + a3.z);
        acc.w = (a0.w + a1.w) + (a2.w + a3.w);
        inv = 1.0f / (float)cnt;
    }
    acc.x *= inv; acc.y *= inv; acc.z *= inv; acc.w *= inv;
    float4* o = (float4*)(out + ((long long)b * maxlen + k) * EDIM) + lane;
    *o = acc;
}

extern "C" void kernel_launch(void* const* d_in, const int* in_sizes, int n_in,
                              void* d_out, int out_size, void* d_ws, size_t ws_size,
                              hipStream_t stream) {
    const float* nn_outs = (const float*)d_in[0];
    const int*   batch_x = (const int*)d_in[1];
    float* out = (float*)d_out;

    const int B = NROWS;
    const int maxlen = (out_size - B) / (B * EDIM);      // 256
    float* n_cuts_out = out + (size_t)B * maxlen * EDIM; // tail of d_out

    const int nb_per_row = (maxlen + SEGS_PER_BLOCK - 1) / SEGS_PER_BLOCK;  // 64
    const int blocks = B * nb_per_row;                                      // 2048

    fused_pool_kernel<<<blocks, 256, 0, stream>>>(nn_outs, batch_x,
                                                  maxlen, nb_per_row,
                                                  out, n_cuts_out);
}

// Round 4
// 190.840 us; speedup vs baseline: 1.0663x; 1.0049x over previous
//
#include <hip/hip_runtime.h>

// Problem shape (fixed by the reference): B=32, T=4096, E=256.
#define NROWS 32
#define TLEN  4096
#define EDIM  256
#define PER   (TLEN / 256)      // tokens per thread in the scan = 16
#define SEGS_PER_BLOCK 4        // one segment per wave, 4 waves/block

// ---------------------------------------------------------------------------
// Fused kernel: each block (256 threads) handles 4 segments of one row.
// Phase 1: block redundantly scans its row's batch_x (16 KB, L2-hot across
//          the 64 blocks sharing the row) into LDS cut positions.
// Phase 2: wave w mean-pools segment k0+w; lane l owns features [4l,4l+4).
//          cnt==16 fast path: 16 independent loads in flight (4x MLP).
// ---------------------------------------------------------------------------
__global__ __launch_bounds__(256) void fused_pool_kernel(
    const float* __restrict__ nn,
    const int*  __restrict__ batch_x,
    int maxlen, int nb_per_row,
    float* __restrict__ out,         // [B, maxlen, E]
    float* __restrict__ n_cuts_out)  // [B] fp32 tail of d_out
{
    const int tid  = threadIdx.x;
    const int lane = tid & 63;
    const int w    = tid >> 6;
    const int blk  = blockIdx.x;
    const int b    = blk / nb_per_row;
    const int k0   = (blk - b * nb_per_row) * SEGS_PER_BLOCK;

    // ---- Phase 1: scan row b ----
    __shared__ int s_cuts[TLEN];     // worst-case T cuts
    __shared__ int s_wsum[4];

    const int* row = batch_x + (long long)b * TLEN;
    const int t0 = tid * PER;

    int flags[PER];
#pragma unroll
    for (int j = 0; j < PER; j += 4) {
        const int4 v = *(const int4*)(row + t0 + j);   // 64B-aligned
        flags[j] = v.x; flags[j + 1] = v.y; flags[j + 2] = v.z; flags[j + 3] = v.w;
    }
    int local = 0;
#pragma unroll
    for (int j = 0; j < PER; ++j) local += (flags[j] == 1);

    // wave inclusive prefix (6 shuffle steps)
    int incl = local;
#pragma unroll
    for (int d = 1; d < 64; d <<= 1) {
        const int v = __shfl_up(incl, d, 64);
        if (lane >= d) incl += v;
    }
    if (lane == 63) s_wsum[w] = incl;
    __syncthreads();
    const int s0 = s_wsum[0], s1 = s_wsum[1], s2 = s_wsum[2], s3 = s_wsum[3];
    const int wbase = (w > 0 ? s0 : 0) + (w > 1 ? s1 : 0) + (w > 2 ? s2 : 0);
    const int ncuts = s0 + s1 + s2 + s3;

    int idx = wbase + incl - local;  // exclusive prefix
#pragma unroll
    for (int j = 0; j < PER; ++j)
        if (flags[j] == 1) s_cuts[idx++] = t0 + j;
    __syncthreads();

    if (k0 == 0 && tid == 0) n_cuts_out[b] = (float)ncuts;

    // ---- Phase 2: pool segment k = k0 + w ----
    const int k = k0 + w;
    if (k >= maxlen) return;

    float4 acc = make_float4(0.f, 0.f, 0.f, 0.f);
    if (k < ncuts) {
        const int start = (k == 0) ? 0 : (s_cuts[k - 1] + 1);
        const int end   = s_cuts[k];                  // inclusive
        const int cnt   = end - start + 1;
        const float* base = nn + ((long long)b * TLEN + start) * EDIM + lane * 4;

        if (cnt == 16) {
            // fast path: all 16 loads issued back-to-back, independent regs
            float4 v[16];
#pragma unroll
            for (int t = 0; t < 16; ++t)
                v[t] = *(const float4*)(base + (long long)t * EDIM);
            // pairwise tree reduction
#pragma unroll
            for (int s = 1; s < 16; s <<= 1)
#pragma unroll
                for (int t = 0; t < 16; t += 2 * s) {
                    v[t].x += v[t + s].x; v[t].y += v[t + s].y;
                    v[t].z += v[t + s].z; v[t].w += v[t + s].w;
                }
            const float inv = 1.0f / 16.0f;
            acc.x = v[0].x * inv; acc.y = v[0].y * inv;
            acc.z = v[0].z * inv; acc.w = v[0].w * inv;
        } else {
            float4 a0 = make_float4(0.f, 0.f, 0.f, 0.f);
            float4 a1 = a0, a2 = a0, a3 = a0;
            int t = 0;
            for (; t + 4 <= cnt; t += 4) {
                const float4 v0 = *(const float4*)(base + (long long)(t + 0) * EDIM);
                const float4 v1 = *(const float4*)(base + (long long)(t + 1) * EDIM);
                const float4 v2 = *(const float4*)(base + (long long)(t + 2) * EDIM);
                const float4 v3 = *(const float4*)(base + (long long)(t + 3) * EDIM);
                a0.x += v0.x; a0.y += v0.y; a0.z += v0.z; a0.w += v0.w;
                a1.x += v1.x; a1.y += v1.y; a1.z += v1.z; a1.w += v1.w;
                a2.x += v2.x; a2.y += v2.y; a2.z += v2.z; a2.w += v2.w;
                a3.x += v3.x; a3.y += v3.y; a3.z += v3.z; a3.w += v3.w;
            }
            for (; t < cnt; ++t) {
                const float4 v = *(const float4*)(base + (long long)t * EDIM);
                a0.x += v.x; a0.y += v.y; a0.z += v.z; a0.w += v.w;
            }
            const float inv = 1.0f / (float)cnt;
            acc.x = ((a0.x + a1.x) + (a2.x + a3.x)) * inv;
            acc.y = ((a0.y + a1.y) + (a2.y + a3.y)) * inv;
            acc.z = ((a0.z + a1.z) + (a2.z + a3.z)) * inv;
            acc.w = ((a0.w + a1.w) + (a2.w + a3.w)) * inv;
        }
    }
    float4* o = (float4*)(out + ((long long)b * maxlen + k) * EDIM) + lane;
    *o = acc;
}

extern "C" void kernel_launch(void* const* d_in, const int* in_sizes, int n_in,
                              void* d_out, int out_size, void* d_ws, size_t ws_size,
                              hipStream_t stream) {
    const float* nn_outs = (const float*)d_in[0];
    const int*   batch_x = (const int*)d_in[1];
    float* out = (float*)d_out;

    const int B = NROWS;
    const int maxlen = (out_size - B) / (B * EDIM);      // 256
    float* n_cuts_out = out + (size_t)B * maxlen * EDIM; // tail of d_out

    const int nb_per_row = (maxlen + SEGS_PER_BLOCK - 1) / SEGS_PER_BLOCK;  // 64
    const int blocks = B * nb_per_row;                                      // 2048

    fused_pool_kernel<<<blocks, 256, 0, stream>>>(nn_outs, batch_x,
                                                  maxlen, nb_per_row,
                                                  out, n_cuts_out);
}